// Round 11
// baseline (106.778 us; speedup 1.0000x reference)
//
#include <hip/hip_runtime.h>
#include <hip/hip_bf16.h>

typedef __attribute__((ext_vector_type(8))) short bf16x8;
typedef __attribute__((ext_vector_type(4))) float f32x4;
typedef __attribute__((ext_vector_type(2))) float f32x2;

constexpr int P = 8192, C = 8192, D = 256;

__device__ __forceinline__ void gload_lds16(const void* g, void* l) {
    __builtin_amdgcn_global_load_lds((const __attribute__((address_space(1))) void*)g,
                                     (__attribute__((address_space(3))) void*)l, 16, 0, 0);
}

__device__ __forceinline__ unsigned short bfbits(float f) {
    __hip_bfloat16 h = __float2bfloat16(f);
    return __builtin_bit_cast(unsigned short, h);
}

// Normalize rows to unit L2 norm, store bf16. One wave per row, float4 loads.
__global__ __launch_bounds__(256) void prep_kernel(const float* __restrict__ prev,
                                                   const float* __restrict__ cur,
                                                   unsigned short* __restrict__ prevb,
                                                   unsigned short* __restrict__ curb) {
    const int lane = threadIdx.x & 63;
    const int wv = threadIdx.x >> 6;
    const int row = blockIdx.x * 4 + wv;
    const float* src;
    unsigned short* dst;
    int r;
    if (row < P) { src = prev; dst = prevb; r = row; }
    else         { src = cur;  dst = curb;  r = row - P; }
    const float4 v = *(const float4*)(src + (size_t)r * D + lane * 4);
    float ss = v.x * v.x + v.y * v.y + v.z * v.z + v.w * v.w;
#pragma unroll
    for (int off = 32; off; off >>= 1) ss += __shfl_xor(ss, off, 64);
    const float inv = 1.0f / sqrtf(ss);   // norms ~16; eps=1e-6 unreachable
    ushort4 o;
    o.x = bfbits(v.x * inv);
    o.y = bfbits(v.y * inv);
    o.z = bfbits(v.z * inv);
    o.w = bfbits(v.w * inv);
    *(ushort4*)(dst + (size_t)r * D + lane * 4) = o;
}

// 8-phase-template GEMM (m201-style fine interleave — the lever r6-r10 all
// skipped; all capped at ~28% MfmaUtil with coarse phases). 256 blocks x 512
// threads (8 waves 2Mx4N, wave tile 128x64). Block = 256 rows x 4 tiles of
// 256 cols (XCD col-slab). 64 phases: each = {ds_read frags -> stage(f+4)
// -> vmcnt(4) -> barrier -> lgkmcnt(0) -> setprio 16-MFMA setprio -> barrier}.
// FIFO ledger: stage(s) = 2 loads, issued phase s-4, consumed phase s-(0,1);
// vmcnt(4) after this phase's stage retires everything through s-2 ->
// consumed data provably landed + barrier-published; >=2 half-tiles always
// in flight (never drains to 0 in the loop). LDS: [dbuf][A|B][kh][256x32]
// = 128 KB, granule swizzle pg = g ^ ((row>>1)&3) (2-way = free); read-side
// term constant per thread. A-frags persist across jh phases (24 ds_read
// per wave per K-tile). Regs: acc 128 + afr 32 + pidp 16 + misc ~= 210.
__global__ __attribute__((amdgpu_flat_work_group_size(512, 512), amdgpu_waves_per_eu(2, 2)))
void gemm_bce_kernel(
    const unsigned short* __restrict__ Ab, const unsigned short* __restrict__ Bb,
    const int* __restrict__ pids, const int* __restrict__ cids,
    float* __restrict__ partial) {
    __shared__ short sAB[2][2][2][8192];   // [dbuf][mat A=0/B=1][kh][row*32+pg*8]
    __shared__ float wsum[8];

    const int tid = threadIdx.x;
    const int lane = tid & 63;
    const int wv = tid >> 6;          // 0..7
    const int wm = wv >> 2;           // 0..1 (M half)
    const int wn = wv & 3;            // 0..3 (N quarter)
    const int fr = lane & 15;
    const int fq = lane >> 4;
    const int pgs8 = (fq ^ ((fr >> 1) & 3)) * 8;   // read-side swizzled granule

    const int bid = blockIdx.x;
    const int x4 = (bid & 7) * 4;                  // XCD col-slab base (tiles)
    const int pblock = (bid >> 3) * 256;

    // ---- staging: half-tile s -> {tile, K-tile, A/B, kh}; 2 loads/thread ----
    auto stage = [&](int s) {
        if (s >= 64) return;
        const int kSg = s >> 2;                    // global K-step 0..15
        const int d = kSg & 1;
        const int kt = kSg & 3;
        const int ttl = kSg >> 2;                  // tile 0..3
        const int h = s & 3;
        const int mat = h & 1, kh = h >> 1;
        const unsigned short* srcbase = mat ? Bb + (size_t)((x4 + ttl) * 256) * D
                                            : Ab + (size_t)pblock * D;
        short* ldsbase = &sAB[d][mat][kh][0];
        const int koff = kt * 64 + kh * 32;
#pragma unroll
        for (int i = 0; i < 2; ++i) {
            const int G = i * 512 + tid;
            const int row = G >> 2, pg = G & 3;
            const int gsrc = pg ^ ((row >> 1) & 3);
            gload_lds16(srcbase + (size_t)row * D + koff + gsrc * 8, ldsbase + G * 8);
        }
    };

    // ---- prologue: ids, then first K-tile's 4 half-tiles ----
    int pidp[16];
#pragma unroll
    for (int m = 0; m < 8; ++m)
#pragma unroll
        for (int rp = 0; rp < 2; ++rp) {
            const int base = pblock + wm * 128 + m * 16 + fq * 4 + rp * 2;
            pidp[m * 2 + rp] = (pids[base] & 0xffff) | (pids[base + 1] << 16);
        }
    asm volatile("" ::: "memory");     // keep id loads ahead of stages in FIFO
    stage(0); stage(1); stage(2); stage(3);
    asm volatile("s_waitcnt vmcnt(4)" ::: "memory");   // S0,S1 landed; S2,S3 fly
    asm volatile("s_barrier" ::: "memory");

    // ln(2cosh(x/2)) - ln2 = t/8 - t^2/192 + t^3/2880 - 17t^4/645120, t=x^2
    constexpr float C1 = 0.125f, C2 = -5.2083333e-3f, C3 = 3.4722222e-4f, C4 = -2.6354832e-5f;
    f32x2 sh2 = {0.f, 0.f}, sx2 = {0.f, 0.f};

    for (int tt = 0; tt < 4; ++tt) {
        f32x4 acc[8][4] = {};
        bf16x8 afr[8];

        auto phase = [&](int sst, int dd, int ks, int jh, bool readA) {
            const short* pa = &sAB[dd][0][ks][0];
            const short* pb = &sAB[dd][1][ks][0];
            if (readA) {
#pragma unroll
                for (int m = 0; m < 8; ++m)
                    afr[m] = *(const bf16x8*)(pa + (wm * 128 + m * 16 + fr) * 32 + pgs8);
            }
            bf16x8 bfr[2];
#pragma unroll
            for (int j = 0; j < 2; ++j)
                bfr[j] = *(const bf16x8*)(pb + (wn * 64 + jh * 32 + j * 16 + fr) * 32 + pgs8);
            stage(sst);
            asm volatile("s_waitcnt vmcnt(4)" ::: "memory");
            asm volatile("s_barrier" ::: "memory");
            asm volatile("s_waitcnt lgkmcnt(0)" ::: "memory");
            __builtin_amdgcn_sched_barrier(0);
            __builtin_amdgcn_s_setprio(1);
#pragma unroll
            for (int m = 0; m < 8; ++m)
#pragma unroll
                for (int j = 0; j < 2; ++j)
                    acc[m][jh * 2 + j] = __builtin_amdgcn_mfma_f32_16x16x32_bf16(
                        afr[m], bfr[j], acc[m][jh * 2 + j], 0, 0, 0);
            __builtin_amdgcn_s_setprio(0);
            asm volatile("s_barrier" ::: "memory");
        };

#pragma unroll
        for (int kt = 0; kt < 4; ++kt) {
            const int s0 = (tt * 4 + kt) * 4 + 4;    // stage 1 K-tile ahead
            phase(s0 + 0, kt & 1, 0, 0, true);
            phase(s0 + 1, kt & 1, 0, 1, false);
            phase(s0 + 2, kt & 1, 1, 0, true);
            phase(s0 + 3, kt & 1, 1, 1, false);
        }

        // ---- per-tile fused BCE epilogue (VALU; cid loads only perturb the
        // vmcnt FIFO toward over-retirement — safe). C/D layout: col=lane&15,
        // row=(lane>>4)*4+reg (m89-verified). acc[m][n] col = wn*64+n*16+fr.
        const int c0 = (x4 + tt) * 256 + wn * 64 + fr;
        int cid_r[4];
#pragma unroll
        for (int n = 0; n < 4; ++n) cid_r[n] = cids[c0 + n * 16];
#pragma unroll
        for (int m = 0; m < 8; ++m)
#pragma unroll
            for (int n = 0; n < 4; ++n)
#pragma unroll
                for (int rp = 0; rp < 2; ++rp) {
                    const f32x2 x = {acc[m][n][rp * 2], acc[m][n][rp * 2 + 1]};
                    const f32x2 t2 = x * x;
                    f32x2 q = t2 * C4 + C3;
                    q = t2 * q + C2;
                    q = t2 * q + C1;
                    sh2 = t2 * q + sh2;
                    const int pp = pidp[m * 2 + rp];
                    const f32x2 cc = {
                        ((pp & 0xffff) == cid_r[n]) ? -0.5f : 0.5f,
                        ((pp >> 16)    == cid_r[n]) ? -0.5f : 0.5f};
                    sx2 = x * cc + sx2;
                }
    }

    float lsum = sh2.x + sh2.y + sx2.x + sx2.y;
#pragma unroll
    for (int off = 32; off; off >>= 1) lsum += __shfl_xor(lsum, off, 64);
    if (lane == 0) wsum[wv] = lsum;
    __syncthreads();
    if (tid == 0) {
        float bsum = 0.f;
#pragma unroll
        for (int w = 0; w < 8; ++w) bsum += wsum[w];
        partial[bid] = bsum;
    }
}

// Deterministic final reduction over 256 block partials; adds folded ln2.
__global__ __launch_bounds__(256) void reduce_kernel(const float* __restrict__ part,
                                                     float* __restrict__ out) {
    const int tid = threadIdx.x;
    double s = (double)part[tid];
#pragma unroll
    for (int off = 32; off; off >>= 1) s += __shfl_xor(s, off, 64);
    __shared__ double red[4];
    const int lane = tid & 63, wv = tid >> 6;
    if (lane == 0) red[wv] = s;
    __syncthreads();
    if (tid == 0)
        out[0] = (float)((red[0] + red[1] + red[2] + red[3]) * (1.0 / ((double)P * (double)C))
                         + 0.69314718055994531);
}

extern "C" void kernel_launch(void* const* d_in, const int* in_sizes, int n_in,
                              void* d_out, int out_size, void* d_ws, size_t ws_size,
                              hipStream_t stream) {
    const float* prev_feat = (const float*)d_in[0];
    const float* cur_feat  = (const float*)d_in[1];
    const int* prev_ids    = (const int*)d_in[2];
    const int* cur_ids     = (const int*)d_in[3];
    float* out = (float*)d_out;

    char* ws = (char*)d_ws;
    unsigned short* prevb = (unsigned short*)ws;                          // 4 MB
    unsigned short* curb  = (unsigned short*)(ws + (size_t)P * D * 2);    // 4 MB
    float* partial = (float*)(ws + (size_t)(P + C) * D * 2);              // 1 KB

    prep_kernel<<<(P + C) / 4, 256, 0, stream>>>(prev_feat, cur_feat, prevb, curb);
    gemm_bce_kernel<<<256, 512, 0, stream>>>(prevb, curb, prev_ids, cur_ids, partial);
    reduce_kernel<<<1, 256, 0, stream>>>(partial, out);
}

// Round 12
// 90.086 us; speedup vs baseline: 1.1853x; 1.1853x over previous
//
#include <hip/hip_runtime.h>
#include <hip/hip_bf16.h>

typedef __attribute__((ext_vector_type(8))) short bf16x8;
typedef __attribute__((ext_vector_type(4))) float f32x4;
typedef __attribute__((ext_vector_type(2))) float f32x2;

constexpr int P = 8192, C = 8192, D = 256;

__device__ __forceinline__ unsigned short bfbits(float f) {
    __hip_bfloat16 h = __float2bfloat16(f);
    return __builtin_bit_cast(unsigned short, h);
}

// Normalize rows to unit L2 norm, store bf16. One wave per row, float4 loads.
__global__ __launch_bounds__(256) void prep_kernel(const float* __restrict__ prev,
                                                   const float* __restrict__ cur,
                                                   unsigned short* __restrict__ prevb,
                                                   unsigned short* __restrict__ curb) {
    const int lane = threadIdx.x & 63;
    const int wv = threadIdx.x >> 6;
    const int row = blockIdx.x * 4 + wv;
    const float* src;
    unsigned short* dst;
    int r;
    if (row < P) { src = prev; dst = prevb; r = row; }
    else         { src = cur;  dst = curb;  r = row - P; }
    const float4 v = *(const float4*)(src + (size_t)r * D + lane * 4);
    float ss = v.x * v.x + v.y * v.y + v.z * v.z + v.w * v.w;
#pragma unroll
    for (int off = 32; off; off >>= 1) ss += __shfl_xor(ss, off, 64);
    const float inv = 1.0f / sqrtf(ss);   // norms ~16; eps=1e-6 unreachable
    ushort4 o;
    o.x = bfbits(v.x * inv);
    o.y = bfbits(v.y * inv);
    o.z = bfbits(v.z * inv);
    o.w = bfbits(v.w * inv);
    *(ushort4*)(dst + (size_t)r * D + lane * 4) = o;
}

// LDS-FREE, BARRIER-FREE GEMM. r6/r7/r8/r10 (four LDS-staged schedules) all
// capped at 26-29% MfmaUtil: per-interval arithmetic shows LDS-read + MFMA +
// VALU summing serially (burst phasing on the shared LDS pipe). Here the
// contended resource is removed: A slab (64 rows x full K) persistent in
// registers per wave; B fragments register-direct from XCD-local L2 (2 MB
// col-slab, L2-resident; 512 MB aggregate ~= 14.8us @ 34.5 TB/s ~ MFMA floor
// 16.6us). 4-deep B prefetch ring (issue u+3 while computing u: ~465 cyc
// cover vs ~200 cyc L2 latency), compiler-managed waitcnts, zero barriers in
// the main loop -> MFMA/VMEM overlap needs no cross-wave phasing.
// Regs: a 128 + acc 32 + bfr 32 + pidp 8 + misc ~= 215 < 256 (2 waves/EU).
// Block: 4 waves x 64 rows = 256 rows; 8 col-tiles of 32 = 256 cols.
// Grid 1024 = 8 XCD-slabs x 4 col-subs x 32 row-blocks.
__global__ __attribute__((amdgpu_flat_work_group_size(256, 256), amdgpu_waves_per_eu(2, 2)))
void gemm_bce_kernel(
    const unsigned short* __restrict__ Ab, const unsigned short* __restrict__ Bb,
    const int* __restrict__ pids, const int* __restrict__ cids,
    float* __restrict__ partial) {
    __shared__ float wsum[4];

    const int tid = threadIdx.x;
    const int lane = tid & 63;
    const int wv = tid >> 6;
    const int bid = blockIdx.x;
    const int xcd = bid & 7;                 // consecutive bids round-robin XCDs
    const int rb = (bid >> 3) & 31;          // row-block 0..31
    const int csub = bid >> 8;               // col-sub 0..3
    const int pblock = rb * 256;
    const int cbase = xcd * 1024 + csub * 256;

    const int fr = lane & 15;
    const int fq = lane >> 4;
    const int kg = fq * 8;

    // ---- A slab -> registers (held for whole kernel): 128 VGPR ----
    const int wrow0 = pblock + wv * 64 + fr;
    bf16x8 a[4][8];
#pragma unroll
    for (int m = 0; m < 4; ++m)
#pragma unroll
        for (int kk = 0; kk < 8; ++kk)
            a[m][kk] = *(const bf16x8*)(Ab + (size_t)(wrow0 + m * 16) * D + kk * 32 + kg);

    int pidp[8];                             // pids packed 2/VGPR (ids < 16384)
#pragma unroll
    for (int m = 0; m < 4; ++m)
#pragma unroll
        for (int rp = 0; rp < 2; ++rp) {
            const int base = pblock + wv * 64 + m * 16 + fq * 4 + rp * 2;
            pidp[m * 2 + rp] = (pids[base] & 0xffff) | (pids[base + 1] << 16);
        }

    // ---- B stream: register-direct from L2, flattened step u = tt*8+kk ----
    auto loadB = [&](int u, int j) -> bf16x8 {
        return *(const bf16x8*)(Bb
            + (size_t)(cbase + (u >> 3) * 32 + j * 16 + fr) * D + (u & 7) * 32 + kg);
    };

    bf16x8 bfr[4][2];
#pragma unroll
    for (int u = 0; u < 3; ++u) {
        bfr[u][0] = loadB(u, 0);
        bfr[u][1] = loadB(u, 1);
    }

    // ln(2cosh(x/2)) - ln2 = t/8 - t^2/192 + t^3/2880 - 17t^4/645120, t=x^2
    constexpr float C1 = 0.125f, C2 = -5.2083333e-3f, C3 = 3.4722222e-4f, C4 = -2.6354832e-5f;
    f32x2 sh2 = {0.f, 0.f}, sx2 = {0.f, 0.f};

    for (int tt = 0; tt < 8; ++tt) {
        f32x4 acc[4][2] = {};
#pragma unroll
        for (int kk = 0; kk < 8; ++kk) {
            const int u = tt * 8 + kk;
            const int cb = kk & 3;                      // static after unroll
            const int pf = (kk + 3) & 3;                // 8 % 4 == 0 keeps it static
            if (kk < 5) {                               // u+3 stays in this/next tile
                bfr[pf][0] = loadB(u + 3, 0);
                bfr[pf][1] = loadB(u + 3, 1);
            } else if (tt < 7) {
                bfr[pf][0] = loadB(u + 3, 0);
                bfr[pf][1] = loadB(u + 3, 1);
            }
#pragma unroll
            for (int m = 0; m < 4; ++m)
#pragma unroll
                for (int j = 0; j < 2; ++j)
                    acc[m][j] = __builtin_amdgcn_mfma_f32_16x16x32_bf16(
                        a[m][kk], bfr[cb][j], acc[m][j], 0, 0, 0);
        }
        // ---- per-tile fused BCE epilogue (pure VALU; no sync) ----
        // C/D layout: col=lane&15, row=(lane>>4)*4+reg (m89-verified).
        const int c0 = cbase + tt * 32 + fr;
        int cid_r[2];
#pragma unroll
        for (int j = 0; j < 2; ++j) cid_r[j] = cids[c0 + j * 16];
#pragma unroll
        for (int m = 0; m < 4; ++m)
#pragma unroll
            for (int j = 0; j < 2; ++j)
#pragma unroll
                for (int rp = 0; rp < 2; ++rp) {
                    const f32x2 x = {acc[m][j][rp * 2], acc[m][j][rp * 2 + 1]};
                    const f32x2 t2 = x * x;
                    f32x2 q = t2 * C4 + C3;
                    q = t2 * q + C2;
                    q = t2 * q + C1;
                    sh2 = t2 * q + sh2;
                    const int pp = pidp[m * 2 + rp];
                    const f32x2 cc = {
                        ((pp & 0xffff) == cid_r[j]) ? -0.5f : 0.5f,
                        ((pp >> 16)    == cid_r[j]) ? -0.5f : 0.5f};
                    sx2 = x * cc + sx2;
                }
    }

    float lsum = sh2.x + sh2.y + sx2.x + sx2.y;
#pragma unroll
    for (int off = 32; off; off >>= 1) lsum += __shfl_xor(lsum, off, 64);
    if (lane == 0) wsum[wv] = lsum;
    __syncthreads();
    if (tid == 0)
        partial[bid] = wsum[0] + wsum[1] + wsum[2] + wsum[3];
}

// Deterministic final reduction over 1024 block partials; adds folded ln2.
__global__ __launch_bounds__(256) void reduce_kernel(const float* __restrict__ part,
                                                     float* __restrict__ out) {
    const int tid = threadIdx.x;
    double s = 0.0;
    for (int i = tid; i < 1024; i += 256) s += (double)part[i];
#pragma unroll
    for (int off = 32; off; off >>= 1) s += __shfl_xor(s, off, 64);
    __shared__ double red[4];
    const int lane = tid & 63, wv = tid >> 6;
    if (lane == 0) red[wv] = s;
    __syncthreads();
    if (tid == 0)
        out[0] = (float)((red[0] + red[1] + red[2] + red[3]) * (1.0 / ((double)P * (double)C))
                         + 0.69314718055994531);
}

extern "C" void kernel_launch(void* const* d_in, const int* in_sizes, int n_in,
                              void* d_out, int out_size, void* d_ws, size_t ws_size,
                              hipStream_t stream) {
    const float* prev_feat = (const float*)d_in[0];
    const float* cur_feat  = (const float*)d_in[1];
    const int* prev_ids    = (const int*)d_in[2];
    const int* cur_ids     = (const int*)d_in[3];
    float* out = (float*)d_out;

    char* ws = (char*)d_ws;
    unsigned short* prevb = (unsigned short*)ws;                          // 4 MB
    unsigned short* curb  = (unsigned short*)(ws + (size_t)P * D * 2);    // 4 MB
    float* partial = (float*)(ws + (size_t)(P + C) * D * 2);              // 4 KB

    prep_kernel<<<(P + C) / 4, 256, 0, stream>>>(prev_feat, cur_feat, prevb, curb);
    gemm_bce_kernel<<<1024, 256, 0, stream>>>(prevb, curb, prev_ids, cur_ids, partial);
    reduce_kernel<<<1, 256, 0, stream>>>(partial, out);
}

// Round 13
// 53.429 us; speedup vs baseline: 1.9985x; 1.6861x over previous
//
#include <hip/hip_runtime.h>
#include <hip/hip_bf16.h>

typedef __attribute__((ext_vector_type(8))) short bf16x8;
typedef __attribute__((ext_vector_type(4))) float f32x4;
typedef __attribute__((ext_vector_type(2))) float f32x2;

constexpr int P = 8192, C = 8192, D = 256;

__device__ __forceinline__ void gload_lds16(const void* g, void* l) {
    __builtin_amdgcn_global_load_lds((const __attribute__((address_space(1))) void*)g,
                                     (__attribute__((address_space(3))) void*)l, 16, 0, 0);
}

__device__ __forceinline__ unsigned short bfbits(float f) {
    __hip_bfloat16 h = __float2bfloat16(f);
    return __builtin_bit_cast(unsigned short, h);
}

// Normalize rows to unit L2 norm, store bf16. One wave per row, float4 loads.
__global__ __launch_bounds__(256) void prep_kernel(const float* __restrict__ prev,
                                                   const float* __restrict__ cur,
                                                   unsigned short* __restrict__ prevb,
                                                   unsigned short* __restrict__ curb) {
    const int lane = threadIdx.x & 63;
    const int wv = threadIdx.x >> 6;
    const int row = blockIdx.x * 4 + wv;
    const float* src;
    unsigned short* dst;
    int r;
    if (row < P) { src = prev; dst = prevb; r = row; }
    else         { src = cur;  dst = curb;  r = row - P; }
    const float4 v = *(const float4*)(src + (size_t)r * D + lane * 4);
    float ss = v.x * v.x + v.y * v.y + v.z * v.z + v.w * v.w;
#pragma unroll
    for (int off = 32; off; off >>= 1) ss += __shfl_xor(ss, off, 64);
    const float inv = 1.0f / sqrtf(ss);
    ushort4 o;
    o.x = bfbits(v.x * inv);
    o.y = bfbits(v.y * inv);
    o.z = bfbits(v.z * inv);
    o.w = bfbits(v.w * inv);
    *(ushort4*)(dst + (size_t)r * D + lane * 4) = o;
}

// 16 MFMA on one C-quadrant; MH/NH must be literals (static acc indices).
#define MMBLK(MH, NH)                                                          \
    do {                                                                       \
        __builtin_amdgcn_s_setprio(1);                                         \
        _Pragma("unroll") for (int mq = 0; mq < 4; ++mq)                       \
            _Pragma("unroll") for (int nq = 0; nq < 2; ++nq)                   \
                _Pragma("unroll") for (int ks = 0; ks < 2; ++ks)               \
                    acc[(MH)*4 + mq][(NH)*2 + nq] =                            \
                        __builtin_amdgcn_mfma_f32_16x16x32_bf16(               \
                            afr[mq][ks], bfr[nq][ks],                          \
                            acc[(MH)*4 + mq][(NH)*2 + nq], 0, 0, 0);           \
        __builtin_amdgcn_s_setprio(0);                                         \
    } while (0)

#define SBAR() asm volatile("s_barrier" ::: "memory")

// Disciplined m201-template port. 256 blocks (1/CU) x 512 thr (8 waves 2Mx4N,
// wave tile 128x64). Block = 256 rows x 4 col-tiles of 256. Per K-tile
// (BK=64) 4 zigzag phases A0B0 -> B1 -> A1 -> B0 (frag reuse: 28 ds_read/
// wave/K-tile; LDS-pipe ~2688 cyc/CU ~= MFMA ~2483/SIMD - balanced).
// Regs by construction: acc 128 + afr 32 + bfr 16 + pidp 16 + misc ~210<256.
// Ledger: half-tile H staged at phase H-5 (prologue H0..4); ONE vmcnt(2) at
// each K-tile's q3-end certifies all of tile u+1's halves (newest was staged
// 2 phases earlier -> wait pre-satisfied, no drain in the loop). WAR safe:
// q3's stage hits the current buffer's A-half0 but every wave's A-reads
// retired into regs before its q2-MFMA, which precedes barrier2(q2), which
// precedes any q3 stage issue.
__global__ __attribute__((amdgpu_flat_work_group_size(512, 512), amdgpu_waves_per_eu(2, 2)))
void gemm_bce_kernel(
    const unsigned short* __restrict__ Ab, const unsigned short* __restrict__ Bb,
    const int* __restrict__ pids, const int* __restrict__ cids,
    float* __restrict__ partial) {
    __shared__ short sL[2][2][16384];   // [dbuf][A=0/B=1][row*64 + pg*8] = 128 KB
    __shared__ float wsum[8];

    const int tid = threadIdx.x;
    const int lane = tid & 63;
    const int wv = tid >> 6;
    const int wm = wv >> 2, wn = wv & 3;
    const int fr = lane & 15, fq = lane >> 4;
    const int bid = blockIdx.x;
    const int cslab = (bid & 7) * 1024;     // XCD col-slab (512 KB B, L2-resident)
    const int pblock = (bid >> 3) * 256;

    // stage half-tile H: u=H>>2 {ct=u>>2, ktl=u&3, d=u&1}, h=H&3 {mat=h>>1, half=h&1}
    auto stage = [&](int H) {
        if (H >= 64) return;
        const int u = H >> 2, h = H & 3;
        const int mat = h >> 1, half = h & 1;
        const int ct = u >> 2, ktl = u & 3, d = u & 1;
        const unsigned short* base = mat ? Bb + (size_t)(cslab + ct * 256) * D
                                         : Ab + (size_t)pblock * D;
        short* dst0 = &sL[d][mat][half * 8192];
        const int koff = ktl * 64;
#pragma unroll
        for (int i = 0; i < 2; ++i) {
            const int G = i * 512 + tid;
            const int rr = G >> 3, pg = G & 7;
            const int gsrc = pg ^ (rr & 7);
            gload_lds16(base + (size_t)(half * 128 + rr) * D + koff + gsrc * 8,
                        dst0 + G * 8);
        }
    };

    // pids packed 2/reg; rows: wm*128 + (m>>2)*64 + (m&3)*16 + fq*4 + rp*2
    int pidp[16];
#pragma unroll
    for (int m = 0; m < 8; ++m)
#pragma unroll
        for (int rp = 0; rp < 2; ++rp) {
            const int base = pblock + wm * 128 + (m >> 2) * 64 + (m & 3) * 16 + fq * 4 + rp * 2;
            pidp[m * 2 + rp] = (pids[base] & 0xffff) | (pids[base + 1] << 16);
        }
    asm volatile("" ::: "memory");   // pid loads stay ahead of stages in FIFO

    stage(0); stage(1); stage(2); stage(3); stage(4);
    asm volatile("s_waitcnt vmcnt(2)" ::: "memory");   // H0..3 landed; H4 flies
    SBAR();

    constexpr float C1 = 0.125f, C2 = -5.2083333e-3f, C3 = 3.4722222e-4f, C4 = -2.6354832e-5f;
    f32x2 sh2 = {0.f, 0.f}, sx2 = {0.f, 0.f};
    f32x4 acc[8][4];
    bf16x8 afr[4][2], bfr[2][2];

    for (int u = 0; u < 16; ++u) {
        const int d = u & 1, ct = u >> 2, ktl = u & 3;
        const short* pa = &sL[d][0][0];
        const short* pb = &sL[d][1][0];
        const int p5 = u * 4 + 5;

        if (ktl == 0) {
#pragma unroll
            for (int m = 0; m < 8; ++m)
#pragma unroll
                for (int n = 0; n < 4; ++n) acc[m][n] = (f32x4){0.f, 0.f, 0.f, 0.f};
        }

        auto rdA = [&](int mh) {
#pragma unroll
            for (int mq = 0; mq < 4; ++mq)
#pragma unroll
                for (int ks = 0; ks < 2; ++ks) {
                    const int row = wm * 128 + mh * 64 + mq * 16 + fr;
                    const int pg = (ks * 4 + fq) ^ (row & 7);
                    afr[mq][ks] = *(const bf16x8*)(pa + row * 64 + pg * 8);
                }
        };
        auto rdB = [&](int nh) {
#pragma unroll
            for (int nq = 0; nq < 2; ++nq)
#pragma unroll
                for (int ks = 0; ks < 2; ++ks) {
                    const int row = wn * 64 + nh * 32 + nq * 16 + fr;
                    const int pg = (ks * 4 + fq) ^ (row & 7);
                    bfr[nq][ks] = *(const bf16x8*)(pb + row * 64 + pg * 8);
                }
        };

        // q0: A0 + B0
        rdA(0); rdB(0); stage(p5 + 0); SBAR(); MMBLK(0, 0); SBAR();
        // q1: B1 (reuse A0)
        rdB(1);         stage(p5 + 1); SBAR(); MMBLK(0, 1); SBAR();
        // q2: A1 (reuse B1)
        rdA(1);         stage(p5 + 2); SBAR(); MMBLK(1, 1); SBAR();
        // q3: B0 again (reuse A1); K-tile-boundary counted wait
        rdB(0);         stage(p5 + 3); SBAR(); MMBLK(1, 0);
        asm volatile("s_waitcnt vmcnt(2)" ::: "memory");
        SBAR();

        if (ktl == 3) {
            // fused BCE epilogue for col-tile ct.
            // C/D layout: col=lane&15, row=(lane>>4)*4+reg (m89-verified).
            int cid_r[4];
#pragma unroll
            for (int n = 0; n < 4; ++n)
                cid_r[n] = cids[cslab + ct * 256 + wn * 64 + (n >> 1) * 32 + (n & 1) * 16 + fr];
#pragma unroll
            for (int m = 0; m < 8; ++m)
#pragma unroll
                for (int n = 0; n < 4; ++n)
#pragma unroll
                    for (int rp = 0; rp < 2; ++rp) {
                        const f32x2 x = {acc[m][n][rp * 2], acc[m][n][rp * 2 + 1]};
                        const f32x2 t2 = x * x;
                        f32x2 q = t2 * C4 + C3;
                        q = t2 * q + C2;
                        q = t2 * q + C1;
                        sh2 = t2 * q + sh2;
                        const int pp = pidp[m * 2 + rp];
                        const f32x2 cc = {
                            ((pp & 0xffff) == cid_r[n]) ? -0.5f : 0.5f,
                            ((pp >> 16)    == cid_r[n]) ? -0.5f : 0.5f};
                        sx2 = x * cc + sx2;
                    }
        }
    }

    float lsum = sh2.x + sh2.y + sx2.x + sx2.y;
#pragma unroll
    for (int off = 32; off; off >>= 1) lsum += __shfl_xor(lsum, off, 64);
    if (lane == 0) wsum[wv] = lsum;
    __syncthreads();
    if (tid == 0) {
        float bsum = 0.f;
#pragma unroll
        for (int w = 0; w < 8; ++w) bsum += wsum[w];
        partial[bid] = bsum;
    }
}

// Deterministic final reduction over 256 block partials; adds folded ln2.
__global__ __launch_bounds__(256) void reduce_kernel(const float* __restrict__ part,
                                                     float* __restrict__ out) {
    const int tid = threadIdx.x;
    double s = (double)part[tid];
#pragma unroll
    for (int off = 32; off; off >>= 1) s += __shfl_xor(s, off, 64);
    __shared__ double red[4];
    const int lane = tid & 63, wv = tid >> 6;
    if (lane == 0) red[wv] = s;
    __syncthreads();
    if (tid == 0)
        out[0] = (float)((red[0] + red[1] + red[2] + red[3]) * (1.0 / ((double)P * (double)C))
                         + 0.69314718055994531);
}

extern "C" void kernel_launch(void* const* d_in, const int* in_sizes, int n_in,
                              void* d_out, int out_size, void* d_ws, size_t ws_size,
                              hipStream_t stream) {
    const float* prev_feat = (const float*)d_in[0];
    const float* cur_feat  = (const float*)d_in[1];
    const int* prev_ids    = (const int*)d_in[2];
    const int* cur_ids     = (const int*)d_in[3];
    float* out = (float*)d_out;

    char* ws = (char*)d_ws;
    unsigned short* prevb = (unsigned short*)ws;                          // 4 MB
    unsigned short* curb  = (unsigned short*)(ws + (size_t)P * D * 2);    // 4 MB
    float* partial = (float*)(ws + (size_t)(P + C) * D * 2);              // 1 KB

    prep_kernel<<<(P + C) / 4, 256, 0, stream>>>(prev_feat, cur_feat, prevb, curb);
    gemm_bce_kernel<<<256, 512, 0, stream>>>(prevb, curb, prev_ids, cur_ids, partial);
    reduce_kernel<<<1, 256, 0, stream>>>(partial, out);
}